// Round 8
// baseline (7634.171 us; speedup 1.0000x reference)
//
#include <hip/hip_runtime.h>
#include <hip/hip_bf16.h>

#if __has_builtin(__builtin_amdgcn_exp2f)
#define EXP2F(x) __builtin_amdgcn_exp2f(x)
#else
#define EXP2F(x) exp2f(x)
#endif
#if __has_builtin(__builtin_amdgcn_rcpf)
#define RCPF(x) __builtin_amdgcn_rcpf(x)
#else
#define RCPF(x) (1.0f/(x))
#endif

typedef _Float16 h2f16 __attribute__((ext_vector_type(2)));

namespace {
constexpr int   kT   = 127;
constexpr int   kE   = 128;
constexpr int   kB   = 4096;
constexpr int   kNWG = 256;
constexpr int   kGRP = 4;                  // batches processed simultaneously
constexpr int   kBPW = 16;                 // batches per workgroup (4 groups)
constexpr float kLog2e = 1.4426950408889634f;
constexpr float kK2    = 2.8853900817779268f;   // 2*log2(e)
// u32 budget: u2u 32768 + p2h 256 + hc2 640 + act 2048 + 6*512 + 128 + 256 + 132
constexpr int   kSmemBytes = (32768 + 256 + 640 + 2048 + 6 * 512 + 128 + 256 + 132) * 4;

__device__ __forceinline__ unsigned int packf16(float a, float b) {
  h2f16 h = { (_Float16)a, (_Float16)b };
  return __builtin_bit_cast(unsigned int, h);
}

#if __has_builtin(__builtin_amdgcn_fdot2)
__device__ __forceinline__ float fdot2f(unsigned int a, unsigned int b, float c) {
  return __builtin_amdgcn_fdot2(__builtin_bit_cast(h2f16, a),
                                __builtin_bit_cast(h2f16, b), c, false);
}
#else
__device__ __forceinline__ float fdot2f(unsigned int a, unsigned int b, float c) {
  h2f16 ha = __builtin_bit_cast(h2f16, a), hb = __builtin_bit_cast(h2f16, b);
  return c + (float)ha.x * (float)hb.x + (float)ha.y * (float)hb.y;
}
#endif

__device__ __forceinline__ float redsum64(float a) {
#pragma unroll
  for (int m = 1; m < 64; m <<= 1) a += __shfl_xor(a, m, 64);
  return a;
}

// 1024 threads, 16 waves, 4 batches per step-group, 3 barriers/step.
// Thread roles: d8 = tid>>3 (0..127): owns gate rows {i,f,g,o}[d8], proj row d8,
// score row d8, U2 row d8.  sub = tid&7: K-chunk / e-chunk selector.
__global__ __launch_bounds__(1024, 4) void decoder_kernel(
    const float* __restrict__ Xg,    // [B,127,128]
    const float* __restrict__ yh,    // [B,127]
    const float* __restrict__ vdw,   // [128]
    const float* __restrict__ vdb,   // [1]
    const float* __restrict__ Wdhs,  // [128,256]
    const float* __restrict__ Wdhsb, // [128]
    const float* __restrict__ Udw,   // [128,128]
    const float* __restrict__ Udb,   // [128]
    const float* __restrict__ ww,    // [129]
    const float* __restrict__ wb,    // [1]
    const float* __restrict__ Wih,   // [512]
    const float* __restrict__ Whh,   // [512,128]
    const float* __restrict__ bih,   // [512]
    const float* __restrict__ bhh,   // [512]
    const float* __restrict__ fcww,  // [256]
    const float* __restrict__ fcb,   // [1]
    float* __restrict__ out)         // [B]
{
  extern __shared__ char smem[];
  unsigned int* u2u  = (unsigned int*)smem;   // [4][128][64] f16 pairs, 16B chunk c at c^(row&15)
  unsigned int* udw2 = u2u + 3 * 8192;        // staging scratch overlay on slot j=3
  unsigned int* p2h  = u2u + 4 * 8192;        // [4][64] f16 pairs of K2*(proj+b)
  unsigned int* hc2  = p2h + 256;             // [4][160]: pairs in 8 chunks of 16 + 4 pad (stride 20)
  float* act  = (float*)(hc2 + 640);  // [4][4][128] gate dot sums
  float* sc   = act  + 2048;          // [4][128] raw scores
  float* XW   = sc   + 512;           // [4][128] ww . X[t,:]
  float* yc   = XW   + 512;           // [4][128] ww[128]*y + wb
  float* beta = yc   + 512;           // [4][128] softmax (last step only)
  float* hl   = beta + 512;           // [4][128] final h
  float* ctxl = hl   + 512;           // [4][128] final ctx
  float* udbl = ctxl + 512;           // [128]
  float* fcw  = udbl + 128;           // [256]
  float* wwl  = fcw  + 256;           // [132]

  const int tid  = threadIdx.x;
  const int d8   = tid >> 3;          // 0..127
  const int sub  = tid & 7;
  const int lane = tid & 63;

  // ---- pinned per-thread weights: 66 persistent regs ----
  unsigned int whh[32];               // 4 gates x 8 pairs, rows g*128+d8, K in [sub*16,+16)
#pragma unroll
  for (int g = 0; g < 4; ++g)
#pragma unroll
    for (int p = 0; p < 8; ++p)
      whh[g * 8 + p] = packf16(Whh[(g * 128 + d8) * 128 + sub * 16 + 2 * p],
                               Whh[(g * 128 + d8) * 128 + sub * 16 + 2 * p + 1]);
  unsigned int wdq[16];               // proj row d8, K in [sub*32,+32) of concat(h,c)
#pragma unroll
  for (int q = 0; q < 16; ++q)
    wdq[q] = packf16(Wdhs[d8 * 256 + sub * 32 + 2 * q],
                     Wdhs[d8 * 256 + sub * 32 + 2 * q + 1]);
  unsigned int v2p[8];                // -2*v_d, e in [sub*16,+16), f16 pairs
#pragma unroll
  for (int i = 0; i < 8; ++i)
    v2p[i] = packf16(-2.0f * vdw[sub * 16 + 2 * i], -2.0f * vdw[sub * 16 + 2 * i + 1]);
  float bi4[4], wi4[4];
#pragma unroll
  for (int g = 0; g < 4; ++g) {
    bi4[g] = bih[g * 128 + d8] + bhh[g * 128 + d8];
    wi4[g] = Wih[g * 128 + d8];
  }
  float wdbp = Wdhsb[d8];
#pragma unroll
  for (int p = 0; p < 32; ++p) asm volatile("" : "+v"(whh[p]));
#pragma unroll
  for (int q = 0; q < 16; ++q) asm volatile("" : "+v"(wdq[q]));
#pragma unroll
  for (int i = 0; i < 8; ++i) asm volatile("" : "+v"(v2p[i]));
#pragma unroll
  for (int g = 0; g < 4; ++g) { asm volatile("" : "+v"(bi4[g])); asm volatile("" : "+v"(wi4[g])); }
  asm volatile("" : "+v"(wdbp));

  // ---- one-time constants ----
  if (tid < 132) wwl[tid] = (tid < 129) ? ww[tid] : ((tid == 129) ? wb[0] : 0.f);
  if (tid < 256) fcw[tid] = fcww[tid];
  if (tid < 128) udbl[tid] = Udb[tid];
  (void)vdb;   // constant shift, cancels in softmax

  for (int grp = 0; grp < kBPW / kGRP; ++grp) {
    const int b0 = blockIdx.x * kBPW + grp * kGRP;
    float creg[kGRP] = {0.f, 0.f, 0.f, 0.f};
    __syncthreads();   // previous group done with LDS

    // ---- S1: stage Udw f16 (swizzled) into slot3 scratch + init state/yc/XW pad ----
    {
      const int r = tid >> 3, mb = (tid & 7) * 2;
#pragma unroll
      for (int ch = 0; ch < 2; ++ch) {
        const int m = mb + ch;
        const float4 wa = *(const float4*)&Udw[r * kE + m * 8];
        const float4 wb4 = *(const float4*)&Udw[r * kE + m * 8 + 4];
        uint4 st;
        st.x = packf16(wa.x, wa.y);  st.y = packf16(wa.z, wa.w);
        st.z = packf16(wb4.x, wb4.y); st.w = packf16(wb4.z, wb4.w);
        *(uint4*)&udw2[r * 64 + ((m ^ (r >> 4)) << 2)] = st;
      }
    }
    if (tid < 640) hc2[tid] = 0u;
    if (tid < 512) {
      const int j = tid >> 7, s2 = tid & 127;
      yc[tid] = (s2 < kT) ? wwl[128] * yh[(size_t)(b0 + j) * kT + s2] + wwl[129] : 0.f;
      if (s2 == 127) XW[tid] = 0.f;
    }
    __syncthreads();

    // ---- S2: U2 = K2*(X @ Udw^T + Udb) (f16, swizzled) + XW, 4 batches ----
    uint4 st3a, st3b;
    if (d8 < kT) {
#pragma unroll
      for (int j = 0; j < kGRP; ++j) {
        const float* Xrow = Xg + (size_t)(b0 + j) * (kT * kE) + d8 * kE;
        float a = 0.f;
#pragma unroll
        for (int q = 0; q < 4; ++q) {
          const float4 xv = *(const float4*)&Xrow[sub * 16 + q * 4];
          const float4 wv = *(const float4*)&wwl[sub * 16 + q * 4];
          a += xv.x * wv.x + xv.y * wv.y + xv.z * wv.z + xv.w * wv.w;
        }
        a += __shfl_xor(a, 1, 64);
        a += __shfl_xor(a, 2, 64);
        a += __shfl_xor(a, 4, 64);
        if (sub == 0) XW[j * 128 + d8] = a;
        float acc[16];
#pragma unroll
        for (int jj = 0; jj < 16; ++jj) acc[jj] = 0.f;
        for (int m = 0; m < 16; ++m) {
          const float4 xa = *(const float4*)&Xrow[m * 8];
          const float4 xb4 = *(const float4*)&Xrow[m * 8 + 4];
          const unsigned int xp0 = packf16(xa.x, xa.y), xp1 = packf16(xa.z, xa.w);
          const unsigned int xp2 = packf16(xb4.x, xb4.y), xp3 = packf16(xb4.z, xb4.w);
#pragma unroll
          for (int jj = 0; jj < 16; ++jj) {
            const uint4 wq = *(const uint4*)&udw2[(sub * 16 + jj) * 64 + ((m ^ sub) << 2)];
            acc[jj] = fdot2f(xp3, wq.w, fdot2f(xp2, wq.z,
                      fdot2f(xp1, wq.y, fdot2f(xp0, wq.x, acc[jj]))));
          }
        }
        uint4 s0, s1;
        const int eb = sub * 16;
        s0.x = packf16(kK2 * (acc[0] + udbl[eb + 0]), kK2 * (acc[1] + udbl[eb + 1]));
        s0.y = packf16(kK2 * (acc[2] + udbl[eb + 2]), kK2 * (acc[3] + udbl[eb + 3]));
        s0.z = packf16(kK2 * (acc[4] + udbl[eb + 4]), kK2 * (acc[5] + udbl[eb + 5]));
        s0.w = packf16(kK2 * (acc[6] + udbl[eb + 6]), kK2 * (acc[7] + udbl[eb + 7]));
        s1.x = packf16(kK2 * (acc[8] + udbl[eb + 8]), kK2 * (acc[9] + udbl[eb + 9]));
        s1.y = packf16(kK2 * (acc[10] + udbl[eb + 10]), kK2 * (acc[11] + udbl[eb + 11]));
        s1.z = packf16(kK2 * (acc[12] + udbl[eb + 12]), kK2 * (acc[13] + udbl[eb + 13]));
        s1.w = packf16(kK2 * (acc[14] + udbl[eb + 14]), kK2 * (acc[15] + udbl[eb + 15]));
        if (j < 3) {
          *(uint4*)&u2u[j * 8192 + d8 * 64 + (((sub * 2 + 0) ^ (d8 & 15)) << 2)] = s0;
          *(uint4*)&u2u[j * 8192 + d8 * 64 + (((sub * 2 + 1) ^ (d8 & 15)) << 2)] = s1;
        } else { st3a = s0; st3b = s1; }
      }
    }
    __syncthreads();   // udw2 fully consumed
    if (d8 < kT) {
      *(uint4*)&u2u[3 * 8192 + d8 * 64 + (((sub * 2 + 0) ^ (d8 & 15)) << 2)] = st3a;
      *(uint4*)&u2u[3 * 8192 + d8 * 64 + (((sub * 2 + 1) ^ (d8 & 15)) << 2)] = st3b;
    }
    // (slot-3 stores separated from first read by B1 in the step loop)

    // ================= 127 steps x 4 batches, 3 barriers each =================
    for (int s = 0; s < kT; ++s) {
      // P1: per batch: 4 gate-row partial dots (K-chunk sub*16..+16, 2 b128)
      //     + proj partial (chunk sub*32..+32 of concat(h,c), 4 b128); shfl-reduce over sub.
#pragma unroll
      for (int j = 0; j < kGRP; ++j) {
        const unsigned int* hj = hc2 + j * 160;
        const int gb = (sub >> 1) * 20 + (sub & 1) * 8;
        const uint4 h0 = *(const uint4*)&hj[gb];
        const uint4 h1 = *(const uint4*)&hj[gb + 4];
        const unsigned int hp[8] = {h0.x, h0.y, h0.z, h0.w, h1.x, h1.y, h1.z, h1.w};
        float a0 = 0.f, a1 = 0.f, a2 = 0.f, a3 = 0.f;
#pragma unroll
        for (int p = 0; p < 8; ++p) {
          a0 = fdot2f(whh[p], hp[p], a0);
          a1 = fdot2f(whh[8 + p], hp[p], a1);
          a2 = fdot2f(whh[16 + p], hp[p], a2);
          a3 = fdot2f(whh[24 + p], hp[p], a3);
        }
        const uint4 q0 = *(const uint4*)&hj[sub * 20];
        const uint4 q1 = *(const uint4*)&hj[sub * 20 + 4];
        const uint4 q2 = *(const uint4*)&hj[sub * 20 + 8];
        const uint4 q3 = *(const uint4*)&hj[sub * 20 + 12];
        const unsigned int pq[16] = {q0.x, q0.y, q0.z, q0.w, q1.x, q1.y, q1.z, q1.w,
                                     q2.x, q2.y, q2.z, q2.w, q3.x, q3.y, q3.z, q3.w};
        float pp = 0.f;
#pragma unroll
        for (int q = 0; q < 16; ++q) pp = fdot2f(wdq[q], pq[q], pp);
#pragma unroll
        for (int m = 1; m < 8; m <<= 1) {
          a0 += __shfl_xor(a0, m, 64);
          a1 += __shfl_xor(a1, m, 64);
          a2 += __shfl_xor(a2, m, 64);
          a3 += __shfl_xor(a3, m, 64);
          pp += __shfl_xor(pp, m, 64);
        }
        if (sub == 0) {
          act[(j * 4 + 0) * 128 + d8] = a0;
          act[(j * 4 + 1) * 128 + d8] = a1;
          act[(j * 4 + 2) * 128 + d8] = a2;
          act[(j * 4 + 3) * 128 + d8] = a3;
        }
        const float pv = kK2 * (pp + wdbp);
        const float pvo = __shfl_xor(pv, 8, 64);
        if ((tid & 15) == 0) p2h[j * 64 + (d8 >> 1)] = packf16(pv, pvo);
      }
      __syncthreads();  // B1

      // P3: score row d8, e-chunk [sub*16,+16); packed f16 add, f32 trans
      if (d8 < kT) {
        const int sw = d8 & 15;
#pragma unroll
        for (int j = 0; j < kGRP; ++j) {
          const unsigned int* ur = u2u + j * 8192 + d8 * 64;
          const uint4 ua = *(const uint4*)&ur[(((sub * 2 + 0) ^ sw) << 2)];
          const uint4 ub = *(const uint4*)&ur[(((sub * 2 + 1) ^ sw) << 2)];
          const uint4 pa = *(const uint4*)&p2h[j * 64 + sub * 8];
          const uint4 pb = *(const uint4*)&p2h[j * 64 + sub * 8 + 4];
          const unsigned int uu[8] = {ua.x, ua.y, ua.z, ua.w, ub.x, ub.y, ub.z, ub.w};
          const unsigned int pp[8] = {pa.x, pa.y, pa.z, pa.w, pb.x, pb.y, pb.z, pb.w};
          float sacc = 0.f;
#pragma unroll
          for (int i = 0; i < 8; ++i) {
            const h2f16 xs = __builtin_bit_cast(h2f16, uu[i]) + __builtin_bit_cast(h2f16, pp[i]);
            const h2f16 vv = __builtin_bit_cast(h2f16, v2p[i]);
            sacc += (float)vv.x * RCPF(1.f + EXP2F((float)xs.x));
            sacc += (float)vv.y * RCPF(1.f + EXP2F((float)xs.y));
          }
          sacc += __shfl_xor(sacc, 1, 64);
          sacc += __shfl_xor(sacc, 2, 64);
          sacc += __shfl_xor(sacc, 4, 64);
          if (sub == 0) sc[j * 128 + d8] = sacc;
        }
      }
      __syncthreads();  // B2

      // P4: redundant per-wave softmax + y_tilde; local gates; local LSTM update
      float rden4[kGRP];
      {
        float yt4[kGRP];
#pragma unroll
        for (int j = 0; j < kGRP; ++j) {
          const float e0v = EXP2F(sc[j * 128 + lane] * kLog2e);
          float e1v = 0.f, x1 = 0.f;
          if (lane < 63) {
            e1v = EXP2F(sc[j * 128 + 64 + lane] * kLog2e);
            x1 = XW[j * 128 + 64 + lane];
          }
          float num = e0v * XW[j * 128 + lane] + e1v * x1;
          float den = e0v + e1v;
#pragma unroll
          for (int m = 1; m < 64; m <<= 1) {
            num += __shfl_xor(num, m, 64);
            den += __shfl_xor(den, m, 64);
          }
          rden4[j] = RCPF(den);
          yt4[j] = num * rden4[j] + yc[j * 128 + s];
        }
#pragma unroll
        for (int j = 0; j < kGRP; ++j) {
          const float gi = act[(j * 4 + 0) * 128 + d8] + bi4[0] + yt4[j] * wi4[0];
          const float gf = act[(j * 4 + 1) * 128 + d8] + bi4[1] + yt4[j] * wi4[1];
          const float gg = act[(j * 4 + 2) * 128 + d8] + bi4[2] + yt4[j] * wi4[2];
          const float go = act[(j * 4 + 3) * 128 + d8] + bi4[3] + yt4[j] * wi4[3];
          const float si = RCPF(1.f + EXP2F(-gi * kLog2e));
          const float sf = RCPF(1.f + EXP2F(-gf * kLog2e));
          const float tg = 1.f - 2.f * RCPF(1.f + EXP2F(gg * kK2));
          const float so = RCPF(1.f + EXP2F(-go * kLog2e));
          const float cn = sf * creg[j] + si * tg;
          creg[j] = cn;
          const float th = 1.f - 2.f * RCPF(1.f + EXP2F(cn * kK2));
          const float hn = so * th;
          const float ho = __shfl_xor(hn, 8, 64);
          const float co = __shfl_xor(cn, 8, 64);
          if ((tid & 15) == 0) {
            const int p = d8 >> 1;
            hc2[j * 160 + (p >> 4) * 20 + (p & 15)] = packf16(hn, ho);
            hc2[j * 160 + (4 + (p >> 4)) * 20 + (p & 15)] = packf16(cn, co);
          }
          if (s == kT - 1 && sub == 0) hl[j * 128 + d8] = hn;
        }
      }
      if (s == kT - 1 && tid < 512) {
        const int j = tid >> 7, t2 = tid & 127;
        const float rd = (j == 0) ? rden4[0] : (j == 1) ? rden4[1]
                       : (j == 2) ? rden4[2] : rden4[3];
        beta[tid] = (t2 < kT) ? EXP2F(sc[tid] * kLog2e) * rd : 0.f;
      }
      __syncthreads();  // B3
    }  // steps

    // ---- final ctx in fp32 from global X; then fc (4 outputs) ----
    {
      const int j = tid >> 8, r = tid & 255, e = r >> 1, hf = r & 1;
      const float* Xbj = Xg + (size_t)(b0 + j) * (kT * kE);
      float cacc = 0.f;
#pragma unroll
      for (int i = 0; i < 64; ++i) {
        const int t2 = hf * 64 + i;
        if (t2 < kT) cacc += beta[j * 128 + t2] * Xbj[(size_t)t2 * kE + e];
      }
      cacc += __shfl_xor(cacc, 1, 64);
      if (hf == 0) ctxl[j * 128 + e] = cacc;
    }
    __syncthreads();
    if (tid < 256) {
      const int j = tid >> 6, l = tid & 63;
      float a2 = hl[j * 128 + l] * fcw[l] + hl[j * 128 + 64 + l] * fcw[64 + l]
               + ctxl[j * 128 + l] * fcw[128 + l] + ctxl[j * 128 + 64 + l] * fcw[192 + l];
      a2 = redsum64(a2);
      if (l == 0) out[b0 + j] = a2 + fcb[0];
    }
  }  // group loop
}
}  // namespace

extern "C" void kernel_launch(void* const* d_in, const int* in_sizes, int n_in,
                              void* d_out, int out_size, void* d_ws, size_t ws_size,
                              hipStream_t stream) {
  (void)in_sizes; (void)n_in; (void)d_ws; (void)ws_size; (void)out_size;
  const float* Xg    = (const float*)d_in[0];
  const float* yh    = (const float*)d_in[1];
  const float* vdw   = (const float*)d_in[2];
  const float* vdb   = (const float*)d_in[3];
  const float* Wdhs  = (const float*)d_in[4];
  const float* Wdhsb = (const float*)d_in[5];
  const float* Udw   = (const float*)d_in[6];
  const float* Udb   = (const float*)d_in[7];
  const float* ww    = (const float*)d_in[8];
  const float* wb    = (const float*)d_in[9];
  const float* Wih   = (const float*)d_in[10];
  const float* Whh   = (const float*)d_in[11];
  const float* bih   = (const float*)d_in[12];
  const float* bhh   = (const float*)d_in[13];
  const float* fcww  = (const float*)d_in[14];
  const float* fcb   = (const float*)d_in[15];
  float* out = (float*)d_out;

  hipFuncSetAttribute((const void*)decoder_kernel,
                      hipFuncAttributeMaxDynamicSharedMemorySize, kSmemBytes);
  decoder_kernel<<<dim3(kNWG), dim3(1024), kSmemBytes, stream>>>(
      Xg, yh, vdw, vdb, Wdhs, Wdhsb, Udw, Udb, ww, wb,
      Wih, Whh, bih, bhh, fcww, fcb, out);
}